// Round 16
// baseline (263.691 us; speedup 1.0000x reference)
//
#include <hip/hip_runtime.h>
#include <math.h>

#define BATCH 524288
#define VEC 512
#define SLAB 8192   // rows written by the whole grid per iteration (16 MB sweep)
#define NSLABS (BATCH / SLAB)   // 64

static_assert(NSLABS == 64, "slab count");

typedef float f32x4 __attribute__((ext_vector_type(4)));

// Accurate sincos of an f32 phase value: f64 reduction by pi/2 of the exact
// f32 input, then f32 minimax kernels on [-pi/4, pi/4] (~1e-7 abs error).
// Correctness-proven in round 10 (absmax 3.9e-3). DO NOT change.
__device__ __forceinline__ void sincos_acc(float phf, float& s, float& c) {
    const double two_over_pi = 0.6366197723675814;
    const double pio2        = 1.5707963267948966;
    const double ph  = (double)phf;                 // exact
    const double nd  = rint(ph * two_over_pi);      // |nd| <= ~3.4e4, exact int
    const double red = fma(-nd, pio2, ph);          // |red| <= pi/4, err ~1e-12
    const int    q   = ((int)nd) & 3;               // correct for negative nd
    const float  r   = (float)red;
    const float  r2  = r * r;
    float sp = fmaf(r2, 2.7183114939898219e-6f, -1.9839334836096632e-4f);
    sp = fmaf(r2, sp, 8.3333293858894632e-3f);
    sp = fmaf(r2, sp, -1.6666666641626524e-1f);
    sp = r * fmaf(r2, sp, 1.0f);
    float cp = fmaf(r2, 2.4390448796277409e-5f, -1.3886763774609929e-3f);
    cp = fmaf(r2, cp, 4.1666623323739063e-2f);
    cp = fmaf(r2, cp, -4.9999999725103100e-1f);
    cp = fmaf(r2, cp, 1.0f);
    const bool swp = (q & 1);
    float ss = swp ? cp : sp;
    float cc = swp ? sp : cp;
    s = (q & 2)       ? -ss : ss;
    c = ((q + 1) & 2) ? -cc : cc;
}

__global__ __launch_bounds__(256) void input_layer_kernel(const float* __restrict__ x,
                                                          float* __restrict__ out) {
    __shared__ float xs[2 * NSLABS];            // 128 x-values for this block
    const int tid = threadIdx.x;
    const int b   = blockIdx.x;

    // SWEEPING-FRONT row ownership (A/B vs R13, single variable):
    // iteration k (k < 64), block b writes rows k*8192 + 2b + {0,1}: the
    // WHOLE grid writes one contiguous 16 MB slab per iteration, sweeping
    // the output monotonically (like fillBuffer's single front) instead of
    // 4096 scattered per-block fronts (HBM row-buffer thrash theory).
    // One-time strided x gather: xs[2k+j] = x[k*SLAB + 2b + j].
    if (tid < 2 * NSLABS) xs[tid] = x[(size_t)(tid >> 1) * SLAB + 2 * b + (tid & 1)];

    // FREQUENCY CHAIN -- correctness-critical, verified round 10 (absmax 3.9e-3):
    // ref e-chain = fast-math reciprocal division (XLA:CPU arcp):
    //   e = (i * fl32(1/255)) * 4, NOT true f32 division.
    // pow = accurate exp10 -> matched by CR f64 pow. DO NOT change.
    const int   q      = tid & 127;             // float4 index within row
    const float RCP255 = 1.0f / 255.0f;         // compile-time fl32(1/255)
    const float e0 = ((float)(2 * q)     * RCP255) * 4.0f;
    const float e1 = ((float)(2 * q + 1) * RCP255) * 4.0f;
    const float f0 = (float)pow(10.0, (double)e0);
    const float f1 = (float)pow(10.0, (double)e1);

    __syncthreads();

    const int half = tid >> 7;                  // 0 or 1: which row of the pair
    for (int k = 0; k < NSLABS; ++k) {          // 64 slabs (R15 bug: was 4096)
        const float xv = xs[2 * k + half];      // wave-uniform -> LDS broadcast
        float s0, c0, s1, c1;
        sincos_acc(xv * f0, s0, c0);            // phase rounded to f32, like the ref
        sincos_acc(xv * f1, s1, c1);
        f32x4 o = {s0, c0, s1, c1};
        const size_t row = (size_t)k * SLAB + 2 * b + half;
        f32x4* dst = reinterpret_cast<f32x4*>(out + row * VEC) + q;
        *dst = o;                               // cached store (R13 A/B winner)
    }
}

extern "C" void kernel_launch(void* const* d_in, const int* in_sizes, int n_in,
                              void* d_out, int out_size, void* d_ws, size_t ws_size,
                              hipStream_t stream) {
    const float* x = (const float*)d_in[0];
    float* out = (float*)d_out;
    // 4096 blocks x 256 threads; 64 iterations, each writing one contiguous
    // 8192-row slab across the whole grid.
    input_layer_kernel<<<4096, 256, 0, stream>>>(x, out);
}

// Round 17
// 194.744 us; speedup vs baseline: 1.3540x; 1.3540x over previous
//
#include <hip/hip_runtime.h>
#include <math.h>

#define BATCH 524288
#define VEC 512
#define TPB 1024  // threads per block
#define RPB 1024  // contiguous rows per block; 512 blocks x 1024 rows = 524288

static_assert(BATCH % RPB == 0, "row split");

typedef float f32x4 __attribute__((ext_vector_type(4)));

// Accurate sincos of an f32 phase value: f64 reduction by pi/2 of the exact
// f32 input, then f32 minimax kernels on [-pi/4, pi/4] (~1e-7 abs error).
// Correctness-proven in round 10 (absmax 3.9e-3). DO NOT change.
__device__ __forceinline__ void sincos_acc(float phf, float& s, float& c) {
    const double two_over_pi = 0.6366197723675814;
    const double pio2        = 1.5707963267948966;
    const double ph  = (double)phf;                 // exact
    const double nd  = rint(ph * two_over_pi);      // |nd| <= ~3.4e4, exact int
    const double red = fma(-nd, pio2, ph);          // |red| <= pi/4, err ~1e-12
    const int    q   = ((int)nd) & 3;               // correct for negative nd
    const float  r   = (float)red;
    const float  r2  = r * r;
    float sp = fmaf(r2, 2.7183114939898219e-6f, -1.9839334836096632e-4f);
    sp = fmaf(r2, sp, 8.3333293858894632e-3f);
    sp = fmaf(r2, sp, -1.6666666641626524e-1f);
    sp = r * fmaf(r2, sp, 1.0f);
    float cp = fmaf(r2, 2.4390448796277409e-5f, -1.3886763774609929e-3f);
    cp = fmaf(r2, cp, 4.1666623323739063e-2f);
    cp = fmaf(r2, cp, -4.9999999725103100e-1f);
    cp = fmaf(r2, cp, 1.0f);
    const bool swp = (q & 1);
    float ss = swp ? cp : sp;
    float cc = swp ? sp : cp;
    s = (q & 2)       ? -ss : ss;
    c = ((q + 1) & 2) ? -cc : cc;
}

__global__ __launch_bounds__(TPB) void input_layer_kernel(const float* __restrict__ x,
                                                          float* __restrict__ out) {
    __shared__ float xs[RPB];                   // 4 KB of x for this block
    const int tid  = threadIdx.x;
    const int base = blockIdx.x * RPB;          // this block's contiguous row range

    // One-time x stage (coalesced, 4 KB). Hot loop does ZERO global reads.
    for (int i = tid; i < RPB; i += TPB) xs[i] = x[base + i];

    // FREQUENCY CHAIN -- correctness-critical, verified round 10 (absmax 3.9e-3):
    // ref e-chain = fast-math reciprocal division (XLA:CPU arcp):
    //   e = (i * fl32(1/255)) * 4, NOT true f32 division.
    // pow = accurate exp10 -> matched by CR f64 pow. DO NOT change.
    const int   q      = tid & 127;             // float4 index within row
    const float RCP255 = 1.0f / 255.0f;         // compile-time fl32(1/255)
    const float e0 = ((float)(2 * q)     * RCP255) * 4.0f;
    const float e1 = ((float)(2 * q + 1) * RCP255) * 4.0f;
    const float f0 = (float)pow(10.0, (double)e0);
    const float f1 = (float)pow(10.0, (double)e1);

    __syncthreads();

    // A/B vs R13 (write-stream topology, single variable): 1024-thread
    // blocks own 1024 contiguous rows (2 MiB region), writing 8 contiguous
    // rows = 16 KiB per block-iteration. ~1024 resident streams instead of
    // ~2048, 4x coarser chunks. R16 (fine interleave, 4x worse) showed the
    // gradient points this way.
    const int ro = tid >> 7;                    // 0..7, wave-uniform
    for (int k = 0; k < RPB / 8; ++k) {
        const int   r  = k * 8 + ro;
        const float xv = xs[r];                 // wave-uniform -> LDS broadcast
        float s0, c0, s1, c1;
        sincos_acc(xv * f0, s0, c0);            // phase rounded to f32, like the ref
        sincos_acc(xv * f1, s1, c1);
        f32x4 o = {s0, c0, s1, c1};
        f32x4* dst = reinterpret_cast<f32x4*>(out + (size_t)(base + r) * VEC) + q;
        *dst = o;                               // cached store (R13 A/B winner)
    }
}

extern "C" void kernel_launch(void* const* d_in, const int* in_sizes, int n_in,
                              void* d_out, int out_size, void* d_ws, size_t ws_size,
                              hipStream_t stream) {
    const float* x = (const float*)d_in[0];
    float* out = (float*)d_out;
    input_layer_kernel<<<BATCH / RPB, TPB, 0, stream>>>(x, out);
}